// Round 7
// baseline (480.947 us; speedup 1.0000x reference)
//
#include <hip/hip_runtime.h>
#include <hip/hip_bf16.h>

#define N_NODES 8192
#define F_IN 512
#define F_OUT 256
#define KSPLIT 8
#define KCHUNK (N_NODES / KSPLIT)   // 1024
#define NTILES (KCHUNK / 32)        // 32 tiles of 32 k per block
#define ROWSB 128                   // rows per block (4 waves x 32 rows)

using short8 = __attribute__((ext_vector_type(8))) short;
using f32x4  = __attribute__((ext_vector_type(4))) float;

typedef __attribute__((address_space(3))) void lds_t;
typedef const __attribute__((address_space(1))) void gbl_t;

__device__ __forceinline__ short f2bf(float v) {
    union { float f; unsigned u; } x; x.f = v;
    unsigned r = x.u + 0x7fffu + ((x.u >> 16) & 1u);   // RNE
    return (short)(r >> 16);
}

// A0: w1 = W@a1, w2 = W@a2 (fp32, exact scores via associativity), WTg[c][k] = bf16(W[k][c])
__global__ void k_prep(const float* __restrict__ W, const float* __restrict__ a1,
                       const float* __restrict__ a2, float* __restrict__ w1,
                       float* __restrict__ w2, short* __restrict__ WTg) {
    const int k = blockIdx.x;          // 0..511
    const int l = threadIdx.x;         // 0..63
    float4 wv = *(const float4*)(W + (size_t)k * F_OUT + 4 * l);
    float4 av = *(const float4*)(a1 + 4 * l);
    float4 bv = *(const float4*)(a2 + 4 * l);
    float s1 = wv.x*av.x + wv.y*av.y + wv.z*av.z + wv.w*av.w;
    float s2 = wv.x*bv.x + wv.y*bv.y + wv.z*bv.z + wv.w*bv.w;
    WTg[(size_t)(4*l+0)*F_IN + k] = f2bf(wv.x);
    WTg[(size_t)(4*l+1)*F_IN + k] = f2bf(wv.y);
    WTg[(size_t)(4*l+2)*F_IN + k] = f2bf(wv.z);
    WTg[(size_t)(4*l+3)*F_IN + k] = f2bf(wv.w);
    #pragma unroll
    for (int off = 32; off; off >>= 1) {
        s1 += __shfl_down(s1, off);
        s2 += __shfl_down(s2, off);
    }
    if (l == 0) { w1[k] = s1; w2[k] = s2; }
}

// A1: f1 = x@w1, f2 = x@w2 (one wave per row)
__global__ void k_f12(const float* __restrict__ x, const float* __restrict__ w1,
                      const float* __restrict__ w2, float* __restrict__ f1,
                      float* __restrict__ f2) {
    const int wv = threadIdx.x >> 6, l = threadIdx.x & 63;
    const int i = blockIdx.x * 4 + wv;
    const float* xr = x + (size_t)i * F_IN;
    float s1 = 0.f, s2 = 0.f;
    #pragma unroll
    for (int t = 0; t < 2; ++t) {
        int k = t * 256 + l * 4;
        float4 xv = *(const float4*)(xr + k);
        float4 u  = *(const float4*)(w1 + k);
        float4 v  = *(const float4*)(w2 + k);
        s1 += xv.x*u.x + xv.y*u.y + xv.z*u.z + xv.w*u.w;
        s2 += xv.x*v.x + xv.y*v.y + xv.z*v.z + xv.w*v.w;
    }
    #pragma unroll
    for (int off = 32; off; off >>= 1) {
        s1 += __shfl_down(s1, off);
        s2 += __shfl_down(s2, off);
    }
    if (l == 0) { f1[i] = s1; f2[i] = s2; }
}

// A2: hT[c][i] = bf16( sum_k x[i][k] W[k][c] ), LINEAR layout
__launch_bounds__(256)
__global__ void k_hT(const float* __restrict__ x, const short* __restrict__ WTg,
                     short* __restrict__ hT) {
    __shared__ short x_lds[32 * 64];
    __shared__ short wt_lds[256 * 64];
    const int tid = threadIdx.x;
    const int wv = tid >> 6, l = tid & 63, lg = l >> 4, lr = l & 15;
    const int ibase = blockIdx.x * 32;
    f32x4 acc[4][2];
    #pragma unroll
    for (int a = 0; a < 4; ++a)
        #pragma unroll
        for (int b = 0; b < 2; ++b) acc[a][b] = (f32x4){0.f, 0.f, 0.f, 0.f};
    for (int k0 = 0; k0 < F_IN; k0 += 64) {
        __syncthreads();
        {
            int i = tid >> 3, ch = tid & 7;
            const float* src = x + (size_t)(ibase + i) * F_IN + k0 + ch * 8;
            float4 v0 = *(const float4*)(src);
            float4 v1 = *(const float4*)(src + 4);
            short8 s;
            s[0]=f2bf(v0.x); s[1]=f2bf(v0.y); s[2]=f2bf(v0.z); s[3]=f2bf(v0.w);
            s[4]=f2bf(v1.x); s[5]=f2bf(v1.y); s[6]=f2bf(v1.z); s[7]=f2bf(v1.w);
            *(short8*)&x_lds[i * 64 + 8 * (ch ^ (i & 7))] = s;
        }
        {
            int cb = tid >> 3, ch = tid & 7;
            #pragma unroll
            for (int p = 0; p < 8; ++p) {
                int c = cb + 32 * p;
                short8 s = *(const short8*)(WTg + (size_t)c * F_IN + k0 + ch * 8);
                *(short8*)&wt_lds[c * 64 + 8 * (ch ^ (c & 7))] = s;
            }
        }
        __syncthreads();
        #pragma unroll
        for (int ks = 0; ks < 2; ++ks) {
            short8 bfrag[2], afrag[4];
            #pragma unroll
            for (int it = 0; it < 2; ++it) {
                int i = it * 16 + lr;
                bfrag[it] = *(short8*)&x_lds[i * 64 + 8 * ((lg + 4*ks) ^ (i & 7))];
            }
            #pragma unroll
            for (int ct = 0; ct < 4; ++ct) {
                int c = wv * 64 + ct * 16 + lr;
                afrag[ct] = *(short8*)&wt_lds[c * 64 + 8 * ((lg + 4*ks) ^ (c & 7))];
            }
            #pragma unroll
            for (int ct = 0; ct < 4; ++ct)
                #pragma unroll
                for (int it = 0; it < 2; ++it)
                    acc[ct][it] = __builtin_amdgcn_mfma_f32_16x16x32_bf16(
                        afrag[ct], bfrag[it], acc[ct][it], 0, 0, 0);
        }
    }
    #pragma unroll
    for (int ct = 0; ct < 4; ++ct)
        #pragma unroll
        for (int it = 0; it < 2; ++it)
            #pragma unroll
            for (int r = 0; r < 4; ++r) {
                int c = wv * 64 + ct * 16 + 4 * lg + r;
                int i = ibase + it * 16 + lr;
                hT[(size_t)c * N_NODES + i] = f2bf(acc[ct][it][r]);
            }
}

// B: fused masked-softmax(P) + P@h. Each wave computes 32 output rows (two
// 16-row groups sharing every hT B-fragment ds_read -> LDS reads halved).
// 4-deep LDS tile pipeline, counted vmcnt, ONE s_barrier per 32-k tile.
__launch_bounds__(256, 2)
__global__ void k_attn(const int* __restrict__ adj, const short* __restrict__ hT,
                       const float* __restrict__ f1, const float* __restrict__ f2,
                       float* __restrict__ part, float* __restrict__ psum) {
    __shared__ short h_lds[4 * 8192];   // 4 bufs x [256 rows][32 k] bf16 (chunk^(row&3) image)
    __shared__ float f2_lds[KCHUNK];    // 4 KB
    const int tid = threadIdx.x;
    const int wv = tid >> 6, l = tid & 63, lg = l >> 4, lr = l & 15;
    const int ksid = blockIdx.x & 7;       // one k-slice per XCD (hT slice L2-resident)
    const int rowblk = blockIdx.x >> 3;
    const int r0 = rowblk * ROWSB;
    const int row0 = r0 + wv * 32 + lr;    // group-0 row
    const int row1 = row0 + 16;            // group-1 row
    const int kbeg = ksid * KCHUNK;
    // hT staging: 4 lanes per dest row, src k-chunk pre-swizzled by (row&3)
    const short* hsrcb = hT + (size_t)(wv * 16 + (l >> 2)) * N_NODES + kbeg
                            + ((l & 3) ^ ((l >> 2) & 3)) * 8;
    // adj staging: 2 lanes per row (halves of 32 ints); wave covers its own 32 rows
    const int* asrcb = adj + (size_t)(r0 + wv * 32 + (l >> 1)) * N_NODES + kbeg + (l & 1) * 16;
    const float f1v0 = f1[row0];
    const float f1v1 = f1[row1];
    const float L2E = 1.44269504f;
    f32x4 acc0[16], acc1[16];
    #pragma unroll
    for (int t = 0; t < 16; ++t) {
        acc0[t] = (f32x4){0.f, 0.f, 0.f, 0.f};
        acc1[t] = (f32x4){0.f, 0.f, 0.f, 0.f};
    }
    float ps0 = 0.f, ps1 = 0.f;

    int4 SA[4], SB[4];
    unsigned mA, mB;

#define STAGE(T) do {                                                           \
    _Pragma("unroll")                                                           \
    for (int p = 0; p < 4; ++p)                                                 \
        __builtin_amdgcn_global_load_lds(                                       \
            (gbl_t*)(hsrcb + (size_t)p * 64 * N_NODES + (T) * 32),              \
            (lds_t*)&h_lds[((T) & 3) * 8192 + p * 2048 + wv * 512], 16, 0, 0);  \
} while (0)

#define ADJ(S, T) do {                                                          \
    S[0] = *(const int4*)(asrcb + (T) * 32);                                    \
    S[1] = *(const int4*)(asrcb + (T) * 32 + 4);                                \
    S[2] = *(const int4*)(asrcb + (T) * 32 + 8);                                \
    S[3] = *(const int4*)(asrcb + (T) * 32 + 12);                               \
} while (0)

// pack own 16 ints -> 16-bit mask; redistribute so lane (lr,lg) gets byte
// [lg*8..lg*8+8) of rows (g*16+lr) for g=0,1: MD = byte_g0 | byte_g1<<8
#define PACK(MD, S) do {                                                        \
    unsigned _m = 0;                                                            \
    _Pragma("unroll")                                                           \
    for (int qq = 0; qq < 4; ++qq) {                                            \
        _m |= (S[qq].x > 0 ? 1u : 0u) << (qq * 4);                              \
        _m |= (S[qq].y > 0 ? 2u : 0u) << (qq * 4);                              \
        _m |= (S[qq].z > 0 ? 4u : 0u) << (qq * 4);                              \
        _m |= (S[qq].w > 0 ? 8u : 0u) << (qq * 4);                              \
    }                                                                           \
    unsigned _a0 = (unsigned)__shfl((int)_m, (lr << 1) | (lg >> 1));            \
    unsigned _a1 = (unsigned)__shfl((int)_m, ((16 + lr) << 1) | (lg >> 1));     \
    MD = ((_a0 >> (8 * (lg & 1))) & 0xffu) |                                    \
         (((_a1 >> (8 * (lg & 1))) & 0xffu) << 8);                              \
} while (0)

#define COMPUTE(T, MD) do {                                                     \
    const int bo = ((T) & 3) * 8192;                                            \
    const float4 fa = *(const float4*)&f2_lds[(T) * 32 + lg * 8];               \
    const float4 fb4 = *(const float4*)&f2_lds[(T) * 32 + lg * 8 + 4];          \
    const float f2v[8] = {fa.x, fa.y, fa.z, fa.w, fb4.x, fb4.y, fb4.z, fb4.w};  \
    short8 pa0, pa1;                                                            \
    _Pragma("unroll")                                                           \
    for (int j = 0; j < 8; ++j) {                                               \
        float e0 = f1v0 + f2v[j];                                               \
        float e1 = f1v1 + f2v[j];                                               \
        float le0 = fmaxf(e0, 0.2f * e0);                                       \
        float le1 = fmaxf(e1, 0.2f * e1);                                       \
        float p0 = ((MD) & (1u << j)) ? exp2f(fminf(le0 * L2E, 80.f)) : 0.f;    \
        float p1 = ((MD) & (256u << j)) ? exp2f(fminf(le1 * L2E, 80.f)) : 0.f;  \
        ps0 += p0; ps1 += p1;                                                   \
        pa0[j] = f2bf(p0); pa1[j] = f2bf(p1);                                   \
    }                                                                           \
    __builtin_amdgcn_s_setprio(1);                                              \
    _Pragma("unroll")                                                           \
    for (int t16 = 0; t16 < 16; ++t16) {                                        \
        short8 bfrag = *(short8*)&h_lds[bo + t16 * 512 + lr * 32                \
                                        + (lg ^ (lr & 3)) * 8];                 \
        acc0[t16] = __builtin_amdgcn_mfma_f32_16x16x32_bf16(pa0, bfrag, acc0[t16], 0, 0, 0); \
        acc1[t16] = __builtin_amdgcn_mfma_f32_16x16x32_bf16(pa1, bfrag, acc1[t16], 0, 0, 0); \
    }                                                                           \
    __builtin_amdgcn_s_setprio(0);                                              \
} while (0)

#define BODY(T, SCUR, MCUR, SNXT, MNXT) do {                                    \
    PACK(MNXT, SNXT);                       /* mask for tile T+1 */             \
    ADJ(SCUR, (T) + 2);                                                         \
    STAGE((T) + 2);                                                             \
    asm volatile("s_waitcnt vmcnt(12)" ::: "memory");                           \
    __builtin_amdgcn_s_barrier();                                               \
    __builtin_amdgcn_sched_barrier(0);                                          \
    COMPUTE(T, MCUR);                                                           \
} while (0)

    // prologue: adj tiles 0,1 -> regs; hT tiles 0,1 -> LDS; f2 slice -> LDS
    ADJ(SA, 0); ADJ(SB, 1);
    STAGE(0); STAGE(1);
    *(float4*)&f2_lds[tid * 4] = *(const float4*)(f2 + kbeg + tid * 4);
    PACK(mA, SA);                          // tile 0 mask
    __syncthreads();                       // one-time full drain

    for (int t = 0; t < NTILES - 2; t += 2) {
        BODY(t,     SA, mA, SB, mB);
        BODY(t + 1, SB, mB, SA, mA);
    }
    // tail T = NTILES-2 (even -> MCUR=mA, SNXT=SB): pack last tile, no new issues
    {
        PACK(mB, SB);                      // tile NTILES-1 (compiler waits its ADJ)
        __builtin_amdgcn_s_barrier();
        __builtin_amdgcn_sched_barrier(0);
        COMPUTE(NTILES - 2, mA);
    }
    // tail T = NTILES-1: drain remaining stage, compute
    {
        asm volatile("s_waitcnt vmcnt(0)" ::: "memory");
        __builtin_amdgcn_s_barrier();
        __builtin_amdgcn_sched_barrier(0);
        COMPUTE(NTILES - 1, mB);
    }
#undef STAGE
#undef ADJ
#undef PACK
#undef COMPUTE
#undef BODY

    ps0 += __shfl_xor(ps0, 16);
    ps0 += __shfl_xor(ps0, 32);
    ps1 += __shfl_xor(ps1, 16);
    ps1 += __shfl_xor(ps1, 32);
    if (lg == 0) {
        psum[ksid * N_NODES + row0] = ps0;
        psum[ksid * N_NODES + row1] = ps1;
    }
    float* pb = part + (size_t)ksid * N_NODES * F_OUT;
    #pragma unroll
    for (int t = 0; t < 16; ++t)
        #pragma unroll
        for (int r = 0; r < 4; ++r) {
            int c = t * 16 + lr;
            int rr0 = r0 + wv * 32 + 4 * lg + r;
            pb[(size_t)rr0 * F_OUT + c] = acc0[t][r];
            pb[(size_t)(rr0 + 16) * F_OUT + c] = acc1[t][r];
        }
}

// C: out = ELU( (sum_s part) / (sum_s psum) )
__global__ void k_comb(const float* __restrict__ part, const float* __restrict__ psum,
                       float* __restrict__ out) {
    const int i = blockIdx.x, c = threadIdx.x;
    float o = 0.f, s = 0.f;
    #pragma unroll
    for (int qq = 0; qq < KSPLIT; ++qq) {
        o += part[(size_t)qq * N_NODES * F_OUT + (size_t)i * F_OUT + c];
        s += psum[qq * N_NODES + i];
    }
    float v = o / s;
    out[(size_t)i * F_OUT + c] = (v > 0.f) ? v : expm1f(v);
}

extern "C" void kernel_launch(void* const* d_in, const int* in_sizes, int n_in,
                              void* d_out, int out_size, void* d_ws, size_t ws_size,
                              hipStream_t stream) {
    const float* x  = (const float*)d_in[0];
    const int* adj  = (const int*)d_in[1];
    const float* W  = (const float*)d_in[2];
    const float* a1 = (const float*)d_in[3];
    const float* a2 = (const float*)d_in[4];
    float* out = (float*)d_out;

    // workspace layout (~69 MB)
    short* hT  = (short*)d_ws;                          // [256][8192] bf16 (linear)
    short* WTg = hT + (size_t)F_OUT * N_NODES;          // [256][512] bf16
    float* fb  = (float*)(WTg + (size_t)F_OUT * F_IN);
    float* w1   = fb;
    float* w2   = fb + 512;
    float* f1   = fb + 1024;
    float* f2   = fb + 1024 + N_NODES;
    float* part = fb + 32768;                           // [8][8192][256] f32
    float* psum = part + (size_t)KSPLIT * N_NODES * F_OUT;  // [8][8192] f32

    k_prep<<<F_IN, 64, 0, stream>>>(W, a1, a2, w1, w2, WTg);
    k_f12<<<N_NODES / 4, 256, 0, stream>>>(x, w1, w2, f1, f2);
    k_hT<<<N_NODES / 32, 256, 0, stream>>>(x, WTg, hT);
    k_attn<<<(N_NODES / ROWSB) * KSPLIT, 256, 0, stream>>>(adj, hT, f1, f2, part, psum);
    k_comb<<<N_NODES, 256, 0, stream>>>(part, psum, out);
}